// Round 1
// baseline (124.350 us; speedup 1.0000x reference)
//
#include <hip/hip_runtime.h>

#define BATCH   8
#define NODES   8192
#define CH      128            // CH_IN == CH_OUT
#define NEXP    64
#define TN      16             // nodes per GEMM tile (M = 8*16 = 128 rows)
#define MAXP    (NODES + NEXP * TN)   // padded sorted-list capacity = 9216
#define NTILES  (MAXP / TN)           // 576 blocks

typedef __attribute__((ext_vector_type(8))) short bf16x8;  // 8 bf16 = 4 VGPRs
typedef __attribute__((ext_vector_type(4))) float f32x4;

// fp32 -> bf16 RNE via native cast: compiler fuses pairs into
// v_cvt_pk_bf16_f32 (1 instr / 2 elems) instead of ~4.5 VALU ops/elem
// for the manual bit-trick (m240: scalar cast beats hand-written cvt).
__device__ __forceinline__ bf16x8 cvt8(f32x4 lo, f32x4 hi) {
    bf16x8 r;
    #pragma unroll
    for (int i = 0; i < 4; ++i) {
        r[i]     = (short)__builtin_bit_cast(unsigned short, static_cast<__bf16>(lo[i]));
        r[i + 4] = (short)__builtin_bit_cast(unsigned short, static_cast<__bf16>(hi[i]));
    }
    return r;
}

// ---------------------------------------------------------------------------
// Prep kernel: grid 256 (was 64 — use the whole machine for the W convert).
//  All 256 blocks: convert one quarter of one expert's W (4096 elems) to bf16.
//  Blocks 0..63 additionally counting-sort the node list for expert e:
//   - per-WAVE replicated histogram (wcnt[4][64]) -> 4x less LDS-atomic
//     contention than a single shared array
//   - padded prefix via 6-step __shfl_up scan on wave 0 (was serial t0 loop)
//   - compact matching node ids into sorted[off..off+cnt), pad tail with -1.
// ---------------------------------------------------------------------------
__global__ __launch_bounds__(256)
void prep_kernel(const int* __restrict__ sel, const float* __restrict__ W,
                 short* __restrict__ Wbf, int* __restrict__ sorted)
{
    const int t = threadIdx.x;

    // (a) W convert: flat quarter-chunks, 256 blocks x 2 iters x 8 elems
    {
        const size_t base = (size_t)blockIdx.x * (CH * CH / 4);
        const float* ws = W   + base;
        short*       wd = Wbf + base;
        #pragma unroll
        for (int i = 0; i < 2; ++i) {
            int idx = (i * 256 + t) * 8;
            f32x4 lo = *reinterpret_cast<const f32x4*>(ws + idx);
            f32x4 hi = *reinterpret_cast<const f32x4*>(ws + idx + 4);
            *reinterpret_cast<bf16x8*>(wd + idx) = cvt8(lo, hi);
        }
    }

    const int e = blockIdx.x;
    if (e >= NEXP) return;                 // blocks 64..255: convert-only

    // (b) sort segment for expert e
    const int wv = t >> 6;
    __shared__ int wcnt[4][NEXP];
    __shared__ int s_off, s_cnt, s_total, cursor;
    if (t < NEXP) { wcnt[0][t] = 0; wcnt[1][t] = 0; wcnt[2][t] = 0; wcnt[3][t] = 0; }
    if (t == 0) cursor = 0;
    __syncthreads();

    int myv[NODES / 256];
    #pragma unroll
    for (int i = 0; i < NODES / 256; ++i) {
        myv[i] = sel[i * 256 + t];
        atomicAdd(&wcnt[wv][myv[i]], 1);
    }
    __syncthreads();

    if (t < NEXP) {                        // wave 0 only: scan padded counts
        int c = wcnt[0][t] + wcnt[1][t] + wcnt[2][t] + wcnt[3][t];
        int p = (c + TN - 1) & ~(TN - 1);
        int scan = p;                      // inclusive scan over 64 lanes
        #pragma unroll
        for (int d = 1; d < NEXP; d <<= 1) {
            int v = __shfl_up(scan, d);
            if (t >= d) scan += v;
        }
        if (t == e)        { s_off = scan - p; s_cnt = c; }
        if (t == NEXP - 1) s_total = scan;
    }
    __syncthreads();

    const int off = s_off, myc = s_cnt;
    const int pad = (myc + TN - 1) & ~(TN - 1);

    for (int i = myc + t; i < pad; i += 256) sorted[off + i] = -1;

    if (e == NEXP - 1) {                   // global tail: unused tiles see -1
        for (int i = s_total + t; i < MAXP; i += 256) sorted[i] = -1;
    }

    #pragma unroll
    for (int i = 0; i < NODES / 256; ++i) {
        if (myv[i] == e) {
            int pos = atomicAdd(&cursor, 1);
            sorted[off + pos] = i * 256 + t;   // disjoint from -1 pad region
        }
    }
}

// ---------------------------------------------------------------------------
// Kernel 2: grouped GEMM. Block = one tile of 16 nodes (single expert thanks
// to segment padding). M = 128 rows (row r = node_idx*8 + b), N = 128, K = 128.
// 512 threads = 8 waves (was 4): wave w owns rows [w*16, w*16+16) x 128 cols
// = 1 row-tile x 8 col-tiles of mfma_f32_16x16x32_bf16.
//  - 18 waves/CU resident (was 9) -> latency hiding for the direct global
//    loads without any LDS staging
//  - acc is 32 VGPRs/wave (was 64)
// A converted fp32->bf16 in-register via v_cvt_pk; B read directly as bf16
// from Wbf (L2-resident). Padded rows load node 0 and aren't stored.
// ---------------------------------------------------------------------------
__global__ __launch_bounds__(512)
void gemm_kernel(const float* __restrict__ x, const int* __restrict__ sel,
                 const short* __restrict__ Wbf, float* __restrict__ out,
                 const int* __restrict__ sorted)
{
    __shared__ int s_nodes[TN];
    __shared__ int s_expert;

    const int tid  = threadIdx.x;
    const int tile = blockIdx.x;

    if (tid < TN) s_nodes[tid] = sorted[tile * TN + tid];
    if (tid == 0) {
        int n0 = sorted[tile * TN];
        s_expert = (n0 >= 0) ? sel[n0] : -1;
    }
    __syncthreads();

    const int e = s_expert;
    if (e < 0) return;                       // unused tile

    const int wave = tid >> 6;               // 0..7
    const int lane = tid & 63;
    const int m16  = lane & 15;              // row (A) / col (B,D) within 16-tile
    const int quad = lane >> 4;              // 0..3 -> k-subblock / D-row group

    const int r    = wave * 16 + m16;        // block-local A row
    const int node = s_nodes[r >> 3];
    const int b    = r & 7;
    const int nd   = (node >= 0) ? node : 0; // safe address for pads
    const float* xrow  = x + ((size_t)(b * NODES + nd)) * CH;
    const short* wbase = Wbf + (size_t)e * CH * CH;

    f32x4 acc[8];
    #pragma unroll
    for (int ct = 0; ct < 8; ++ct) acc[ct] = (f32x4){0.f, 0.f, 0.f, 0.f};

    #pragma unroll
    for (int kk = 0; kk < 4; ++kk) {
        const int k0 = kk * 32 + quad * 8;   // this lane's 8-k chunk

        f32x4 lo = *reinterpret_cast<const f32x4*>(xrow + k0);
        f32x4 hi = *reinterpret_cast<const f32x4*>(xrow + k0 + 4);
        bf16x8 afrag = cvt8(lo, hi);

        #pragma unroll
        for (int ct = 0; ct < 8; ++ct) {
            bf16x8 bfrag = *reinterpret_cast<const bf16x8*>(
                wbase + (size_t)(ct * 16 + m16) * CH + k0);   // B[k][n]=W[n][k]
            acc[ct] = __builtin_amdgcn_mfma_f32_16x16x32_bf16(
                          afrag, bfrag, acc[ct], 0, 0, 0);
        }
    }

    // D layout: col = lane&15, row = quad*4 + reg  (m89/m91-verified)
    #pragma unroll
    for (int reg = 0; reg < 4; ++reg) {
        int rr = wave * 16 + quad * 4 + reg;
        int nn = s_nodes[rr >> 3];
        if (nn < 0) continue;                // padded row: drop
        int bb = rr & 7;
        float* orow = out + ((size_t)(bb * NODES + nn)) * CH;
        #pragma unroll
        for (int ct = 0; ct < 8; ++ct)
            orow[ct * 16 + m16] = acc[ct][reg];
    }
}

extern "C" void kernel_launch(void* const* d_in, const int* in_sizes, int n_in,
                              void* d_out, int out_size, void* d_ws, size_t ws_size,
                              hipStream_t stream)
{
    const float* x   = (const float*)d_in[0];
    const int*   sel = (const int*)  d_in[1];
    const float* W   = (const float*)d_in[2];
    float*       out = (float*)d_out;

    short* Wbf    = (short*)d_ws;                             // 2 MiB
    int*   sorted = (int*)((char*)d_ws + (size_t)NEXP * CH * CH * sizeof(short));

    prep_kernel<<<256, 256, 0, stream>>>(sel, W, Wbf, sorted);
    gemm_kernel<<<NTILES, 512, 0, stream>>>(x, sel, Wbf, out, sorted);
}

// Round 2
// 116.759 us; speedup vs baseline: 1.0650x; 1.0650x over previous
//
#include <hip/hip_runtime.h>

#define BATCH   8
#define NODES   8192
#define CH      128            // CH_IN == CH_OUT
#define NEXP    64
#define TN      16             // nodes per GEMM tile (M = 8*16 = 128 rows)
#define MAXP    (NODES + NEXP * TN)   // padded sorted-list capacity = 9216
#define NTILES  (MAXP / TN)           // 576 blocks

typedef __attribute__((ext_vector_type(8))) short bf16x8;  // 8 bf16 = 4 VGPRs
typedef __attribute__((ext_vector_type(4))) float f32x4;

// fp32 -> bf16 RNE via native cast: compiler fuses pairs into
// v_cvt_pk_bf16_f32 (1 instr / 2 elems; m240: scalar cast beats hand-rolled).
__device__ __forceinline__ bf16x8 cvt8(f32x4 lo, f32x4 hi) {
    bf16x8 r;
    #pragma unroll
    for (int i = 0; i < 4; ++i) {
        r[i]     = (short)__builtin_bit_cast(unsigned short, static_cast<__bf16>(lo[i]));
        r[i + 4] = (short)__builtin_bit_cast(unsigned short, static_cast<__bf16>(hi[i]));
    }
    return r;
}

// ---------------------------------------------------------------------------
// Prep kernel: grid 256.
//  All 256 blocks: convert one quarter-chunk of W (4096 elems) to bf16.
//  Blocks 0..63 additionally counting-sort the node list for expert e:
//   per-wave replicated histogram, 6-step __shfl_up padded prefix scan,
//   compact matching node ids, -1 pad tails.
// ---------------------------------------------------------------------------
__global__ __launch_bounds__(256)
void prep_kernel(const int* __restrict__ sel, const float* __restrict__ W,
                 short* __restrict__ Wbf, int* __restrict__ sorted)
{
    const int t = threadIdx.x;

    // (a) W convert: flat quarter-chunks, 256 blocks x 2 iters x 8 elems
    {
        const size_t base = (size_t)blockIdx.x * (CH * CH / 4);
        const float* ws = W   + base;
        short*       wd = Wbf + base;
        #pragma unroll
        for (int i = 0; i < 2; ++i) {
            int idx = (i * 256 + t) * 8;
            f32x4 lo = *reinterpret_cast<const f32x4*>(ws + idx);
            f32x4 hi = *reinterpret_cast<const f32x4*>(ws + idx + 4);
            *reinterpret_cast<bf16x8*>(wd + idx) = cvt8(lo, hi);
        }
    }

    const int e = blockIdx.x;
    if (e >= NEXP) return;                 // blocks 64..255: convert-only

    // (b) sort segment for expert e
    const int wv = t >> 6;
    __shared__ int wcnt[4][NEXP];
    __shared__ int s_off, s_cnt, s_total, cursor;
    if (t < NEXP) { wcnt[0][t] = 0; wcnt[1][t] = 0; wcnt[2][t] = 0; wcnt[3][t] = 0; }
    if (t == 0) cursor = 0;
    __syncthreads();

    int myv[NODES / 256];
    #pragma unroll
    for (int i = 0; i < NODES / 256; ++i) {
        myv[i] = sel[i * 256 + t];
        atomicAdd(&wcnt[wv][myv[i]], 1);
    }
    __syncthreads();

    if (t < NEXP) {                        // wave 0 only: scan padded counts
        int c = wcnt[0][t] + wcnt[1][t] + wcnt[2][t] + wcnt[3][t];
        int p = (c + TN - 1) & ~(TN - 1);
        int scan = p;                      // inclusive scan over 64 lanes
        #pragma unroll
        for (int d = 1; d < NEXP; d <<= 1) {
            int v = __shfl_up(scan, d);
            if (t >= d) scan += v;
        }
        if (t == e)        { s_off = scan - p; s_cnt = c; }
        if (t == NEXP - 1) s_total = scan;
    }
    __syncthreads();

    const int off = s_off, myc = s_cnt;
    const int pad = (myc + TN - 1) & ~(TN - 1);

    for (int i = myc + t; i < pad; i += 256) sorted[off + i] = -1;

    if (e == NEXP - 1) {                   // global tail: unused tiles see -1
        for (int i = s_total + t; i < MAXP; i += 256) sorted[i] = -1;
    }

    #pragma unroll
    for (int i = 0; i < NODES / 256; ++i) {
        if (myv[i] == e) {
            int pos = atomicAdd(&cursor, 1);
            sorted[off + pos] = i * 256 + t;   // disjoint from -1 pad region
        }
    }
}

// ---------------------------------------------------------------------------
// Kernel 2: grouped GEMM, SWAPPED operands: D = W · x^T.
// Block = one tile of 16 nodes (single expert). 256 threads = 4 waves.
// Wave w owns output rows [w*32, w*32+32) (j = node-row, 2 j-tiles) x all
// 128 out-channels (8 ct-tiles). Per kk: 8 W-frag loads (shared across jt),
// 2 x-frag loads, 16 MFMAs.
// Operand swap makes D: col(lane&15) = node-row j, row(quad*4+reg) = out-ch
// -> each lane's f32x4 acc = 4 CONSECUTIVE out-channels of one output row
// -> epilogue is 16 global_store_dwordx4 per lane (was 64 scalar dwords).
// ---------------------------------------------------------------------------
__global__ __launch_bounds__(256)
void gemm_kernel(const float* __restrict__ x, const int* __restrict__ sel,
                 const short* __restrict__ Wbf, float* __restrict__ out,
                 const int* __restrict__ sorted)
{
    __shared__ int s_nodes[TN];
    __shared__ int s_expert;

    const int tid  = threadIdx.x;
    const int tile = blockIdx.x;

    if (tid < TN) s_nodes[tid] = sorted[tile * TN + tid];
    if (tid == 0) {
        int n0 = sorted[tile * TN];
        s_expert = (n0 >= 0) ? sel[n0] : -1;
    }
    __syncthreads();

    const int e = s_expert;
    if (e < 0) return;                       // unused tile

    const int wave = tid >> 6;               // 0..3
    const int lane = tid & 63;
    const int m16  = lane & 15;              // A row (out-ch) / B col (node-row)
    const int quad = lane >> 4;              // k-subblock / D out-ch group

    // x rows this lane feeds as the B operand: j = wave*32 + jt*16 + m16
    int          nodej[2];
    const float* xrow[2];
    #pragma unroll
    for (int jt = 0; jt < 2; ++jt) {
        int j    = wave * 32 + jt * 16 + m16;       // block-local output row
        int node = s_nodes[j >> 3];
        int b    = j & 7;
        nodej[jt] = node;
        int nd   = (node >= 0) ? node : 0;          // safe address for pads
        xrow[jt] = x + ((size_t)(b * NODES + nd)) * CH;
    }
    const short* wbase = Wbf + (size_t)e * CH * CH;

    f32x4 acc[2][8];
    #pragma unroll
    for (int jt = 0; jt < 2; ++jt)
        #pragma unroll
        for (int ct = 0; ct < 8; ++ct)
            acc[jt][ct] = (f32x4){0.f, 0.f, 0.f, 0.f};

    #pragma unroll
    for (int kk = 0; kk < 4; ++kk) {
        const int k0 = kk * 32 + quad * 8;          // this lane's 8-k chunk

        bf16x8 xfrag[2];
        #pragma unroll
        for (int jt = 0; jt < 2; ++jt) {
            const float* p = xrow[jt] + k0;
            f32x4 lo = *reinterpret_cast<const f32x4*>(p);
            f32x4 hi = *reinterpret_cast<const f32x4*>(p + 4);
            xfrag[jt] = cvt8(lo, hi);
        }

        #pragma unroll
        for (int ct = 0; ct < 8; ++ct) {
            // A operand: W row (out-ch) = ct*16 + m16, k = k0..k0+7
            bf16x8 wfrag = *reinterpret_cast<const bf16x8*>(
                wbase + (size_t)(ct * 16 + m16) * CH + k0);
            acc[0][ct] = __builtin_amdgcn_mfma_f32_16x16x32_bf16(
                             wfrag, xfrag[0], acc[0][ct], 0, 0, 0);
            acc[1][ct] = __builtin_amdgcn_mfma_f32_16x16x32_bf16(
                             wfrag, xfrag[1], acc[1][ct], 0, 0, 0);
        }
    }

    // D layout: col(lane&15) = node-row j, row(quad*4+reg) = out-ch within ct
    // -> lane's f32x4 = out[j][ct*16 + quad*4 .. +3]: one dwordx4 store.
    #pragma unroll
    for (int jt = 0; jt < 2; ++jt) {
        int node = nodej[jt];
        if (node < 0) continue;                     // padded row: drop
        int j = wave * 32 + jt * 16 + m16;
        int b = j & 7;
        float* orow = out + ((size_t)(b * NODES + node)) * CH;
        #pragma unroll
        for (int ct = 0; ct < 8; ++ct)
            *reinterpret_cast<f32x4*>(orow + ct * 16 + quad * 4) = acc[jt][ct];
    }
}

extern "C" void kernel_launch(void* const* d_in, const int* in_sizes, int n_in,
                              void* d_out, int out_size, void* d_ws, size_t ws_size,
                              hipStream_t stream)
{
    const float* x   = (const float*)d_in[0];
    const int*   sel = (const int*)  d_in[1];
    const float* W   = (const float*)d_in[2];
    float*       out = (float*)d_out;

    short* Wbf    = (short*)d_ws;                             // 2 MiB
    int*   sorted = (int*)((char*)d_ws + (size_t)NEXP * CH * CH * sizeof(short));

    prep_kernel<<<256, 256, 0, stream>>>(sel, W, Wbf, sorted);
    gemm_kernel<<<NTILES, 256, 0, stream>>>(x, sel, Wbf, out, sorted);
}

// Round 4
// 110.416 us; speedup vs baseline: 1.1262x; 1.0575x over previous
//
#include <hip/hip_runtime.h>

#define BATCH   8
#define NODES   8192
#define CH      128            // CH_IN == CH_OUT
#define NEXP    64
#define TN      16             // nodes per GEMM tile (M = 8*16 = 128 rows)
#define MAXP    (NODES + NEXP * TN)   // padded sorted-list capacity = 9216
#define NTILES  (MAXP / TN)           // 576 blocks
#define NSORT   64                    // sorter blocks / slices
#define SLICE   (NODES / NSORT)       // 128 sel elems per slice

typedef __attribute__((ext_vector_type(8))) short bf16x8;  // 8 bf16 = 4 VGPRs
typedef __attribute__((ext_vector_type(4))) float f32x4;

// fp32 -> bf16 RNE via native cast: compiler fuses pairs into
// v_cvt_pk_bf16_f32 (1 instr / 2 elems; m240: scalar cast beats hand-rolled).
__device__ __forceinline__ bf16x8 cvt8(f32x4 lo, f32x4 hi) {
    bf16x8 r;
    #pragma unroll
    for (int i = 0; i < 4; ++i) {
        r[i]     = (short)__builtin_bit_cast(unsigned short, static_cast<__bf16>(lo[i]));
        r[i + 4] = (short)__builtin_bit_cast(unsigned short, static_cast<__bf16>(hi[i]));
    }
    return r;
}

// ---------------------------------------------------------------------------
// K1 (grid 256): W convert + sorted[]=-1 fill + distributed partial histogram.
//  Blocks 0..63 each histogram ONLY sel[blk*128 .. blk*128+128) into
//  gcnt[blk][64]  (was: 64 blocks x full 8192-elem sel, 8192 LDS atomics each).
// ---------------------------------------------------------------------------
__global__ __launch_bounds__(256)
void prep1_kernel(const int* __restrict__ sel, const float* __restrict__ W,
                  short* __restrict__ Wbf, int* __restrict__ sorted,
                  int* __restrict__ gcnt)
{
    const int t   = threadIdx.x;
    const int blk = blockIdx.x;

    // (a) W convert: flat quarter-chunks, 256 blocks x 2 iters x 8 elems
    {
        const size_t base = (size_t)blk * (CH * CH / 4);
        const float* ws = W   + base;
        short*       wd = Wbf + base;
        #pragma unroll
        for (int i = 0; i < 2; ++i) {
            int idx = (i * 256 + t) * 8;
            f32x4 lo = *reinterpret_cast<const f32x4*>(ws + idx);
            f32x4 hi = *reinterpret_cast<const f32x4*>(ws + idx + 4);
            *reinterpret_cast<bf16x8*>(wd + idx) = cvt8(lo, hi);
        }
    }

    // (b) -1 fill of the whole sorted list (pads + tail keep -1 after scatter)
    {
        const int si = blk * 256 + t;
        if (si < MAXP) sorted[si] = -1;
    }

    // (c) partial histogram for slice blk
    if (blk < NSORT) {
        __shared__ int hist[NEXP];
        if (t < NEXP) hist[t] = 0;
        __syncthreads();
        if (t < SLICE) atomicAdd(&hist[sel[blk * SLICE + t]], 1);
        __syncthreads();
        if (t < NEXP) gcnt[blk * NEXP + t] = hist[t];
    }
}

// ---------------------------------------------------------------------------
// K2 (grid 64): block blk derives padded segment starts from the 64x64
// partial-count matrix (L2-hot), adds its own cross-block prefix, scatters
// its 128-node slice. Positions disjoint across blocks; order within an
// expert segment is irrelevant (gemm treats the tile's nodes as a set).
// ---------------------------------------------------------------------------
__global__ __launch_bounds__(256)
void prep2_kernel(const int* __restrict__ sel, const int* __restrict__ gcnt,
                  int* __restrict__ sorted)
{
    const int t   = threadIdx.x;
    const int blk = blockIdx.x;

    __shared__ int cursor[NEXP];

    if (t < NEXP) {                 // wave 0: one expert per lane
        int cnt = 0, own = 0;
        for (int s = 0; s < NSORT; ++s) {
            int g = gcnt[s * NEXP + t];
            own += (s < blk) ? g : 0;
            cnt += g;
        }
        int p = (cnt + TN - 1) & ~(TN - 1);
        int scan = p;               // inclusive padded scan over 64 experts
        #pragma unroll
        for (int d = 1; d < NEXP; d <<= 1) {
            int v = __shfl_up(scan, d);
            if (t >= d) scan += v;
        }
        cursor[t] = (scan - p) + own;   // segment start + cross-block prefix
    }
    __syncthreads();

    if (t < SLICE) {
        int n = blk * SLICE + t;
        int e = sel[n];
        int pos = atomicAdd(&cursor[e], 1);
        sorted[pos] = n;
    }
}

// ---------------------------------------------------------------------------
// K3: grouped GEMM (round-2 body, unchanged). SWAPPED operands: D = W . x^T.
// Block = one tile of 16 nodes (single expert). 256 threads = 4 waves.
// Wave w owns output rows [w*32, w*32+32) (2 j-tiles) x 128 out-ch (8 ct).
// D: col(lane&15) = node-row j, row(quad*4+reg) = out-ch -> each lane's
// f32x4 acc = 4 consecutive out-channels of one row -> dwordx4 stores.
// ---------------------------------------------------------------------------
__global__ __launch_bounds__(256)
void gemm_kernel(const float* __restrict__ x, const int* __restrict__ sel,
                 const short* __restrict__ Wbf, float* __restrict__ out,
                 const int* __restrict__ sorted)
{
    __shared__ int s_nodes[TN];
    __shared__ int s_expert;

    const int tid  = threadIdx.x;
    const int tile = blockIdx.x;

    if (tid < TN) s_nodes[tid] = sorted[tile * TN + tid];
    if (tid == 0) {
        int n0 = sorted[tile * TN];
        s_expert = (n0 >= 0) ? sel[n0] : -1;
    }
    __syncthreads();

    const int e = s_expert;
    if (e < 0) return;                       // unused tile

    const int wave = tid >> 6;               // 0..3
    const int lane = tid & 63;
    const int m16  = lane & 15;              // A row (out-ch) / B col (node-row)
    const int quad = lane >> 4;              // k-subblock / D out-ch group

    int          nodej[2];
    const float* xrow[2];
    #pragma unroll
    for (int jt = 0; jt < 2; ++jt) {
        int j    = wave * 32 + jt * 16 + m16;       // block-local output row
        int node = s_nodes[j >> 3];
        int b    = j & 7;
        nodej[jt] = node;
        int nd   = (node >= 0) ? node : 0;          // safe address for pads
        xrow[jt] = x + ((size_t)(b * NODES + nd)) * CH;
    }
    const short* wbase = Wbf + (size_t)e * CH * CH;

    f32x4 acc[2][8];
    #pragma unroll
    for (int jt = 0; jt < 2; ++jt)
        #pragma unroll
        for (int ct = 0; ct < 8; ++ct)
            acc[jt][ct] = (f32x4){0.f, 0.f, 0.f, 0.f};

    #pragma unroll
    for (int kk = 0; kk < 4; ++kk) {
        const int k0 = kk * 32 + quad * 8;          // this lane's 8-k chunk

        bf16x8 xfrag[2];
        #pragma unroll
        for (int jt = 0; jt < 2; ++jt) {
            const float* p = xrow[jt] + k0;
            f32x4 lo = *reinterpret_cast<const f32x4*>(p);
            f32x4 hi = *reinterpret_cast<const f32x4*>(p + 4);
            xfrag[jt] = cvt8(lo, hi);
        }

        #pragma unroll
        for (int ct = 0; ct < 8; ++ct) {
            // A operand: W row (out-ch) = ct*16 + m16, k = k0..k0+7
            bf16x8 wfrag = *reinterpret_cast<const bf16x8*>(
                wbase + (size_t)(ct * 16 + m16) * CH + k0);
            acc[0][ct] = __builtin_amdgcn_mfma_f32_16x16x32_bf16(
                             wfrag, xfrag[0], acc[0][ct], 0, 0, 0);
            acc[1][ct] = __builtin_amdgcn_mfma_f32_16x16x32_bf16(
                             wfrag, xfrag[1], acc[1][ct], 0, 0, 0);
        }
    }

    // D layout: col(lane&15) = node-row j, row(quad*4+reg) = out-ch within ct
    #pragma unroll
    for (int jt = 0; jt < 2; ++jt) {
        int node = nodej[jt];
        if (node < 0) continue;                     // padded row: drop
        int j = wave * 32 + jt * 16 + m16;
        int b = j & 7;
        float* orow = out + ((size_t)(b * NODES + node)) * CH;
        #pragma unroll
        for (int ct = 0; ct < 8; ++ct)
            *reinterpret_cast<f32x4*>(orow + ct * 16 + quad * 4) = acc[jt][ct];
    }
}

extern "C" void kernel_launch(void* const* d_in, const int* in_sizes, int n_in,
                              void* d_out, int out_size, void* d_ws, size_t ws_size,
                              hipStream_t stream)
{
    const float* x   = (const float*)d_in[0];
    const int*   sel = (const int*)  d_in[1];
    const float* W   = (const float*)d_in[2];
    float*       out = (float*)d_out;

    short* Wbf    = (short*)d_ws;                             // 2 MiB
    int*   sorted = (int*)((char*)d_ws + (size_t)NEXP * CH * CH * sizeof(short));
    int*   gcnt   = sorted + MAXP;                            // 64x64 partials

    prep1_kernel<<<256, 256, 0, stream>>>(sel, W, Wbf, sorted, gcnt);
    prep2_kernel<<<NSORT, 256, 0, stream>>>(sel, gcnt, sorted);
    gemm_kernel<<<NTILES, 256, 0, stream>>>(x, sel, Wbf, out, sorted);
}

// Round 5
// 102.178 us; speedup vs baseline: 1.2170x; 1.0806x over previous
//
#include <hip/hip_runtime.h>

#define BATCH   8
#define NODES   8192
#define CH      128            // CH_IN == CH_OUT
#define NEXP    64
#define TN      16             // nodes per GEMM tile (M = 8*16 = 128 rows)
#define MAXP    (NODES + NEXP * TN)   // padded sorted-list capacity = 9216
#define NTILES  (MAXP / TN)           // 576 blocks
#define NSORT   64                    // sorter blocks / slices
#define SLICE   (NODES / NSORT)       // 128 sel elems per slice

typedef __attribute__((ext_vector_type(8))) short bf16x8;  // 8 bf16 = 4 VGPRs
typedef __attribute__((ext_vector_type(4))) float f32x4;

typedef const __attribute__((address_space(1))) unsigned int gu32;  // global
typedef __attribute__((address_space(3))) unsigned int lu32;        // LDS

// fp32 -> bf16 RNE via native cast: compiler fuses pairs into
// v_cvt_pk_bf16_f32 (1 instr / 2 elems; m240: scalar cast beats hand-rolled).
__device__ __forceinline__ bf16x8 cvt8(f32x4 lo, f32x4 hi) {
    bf16x8 r;
    #pragma unroll
    for (int i = 0; i < 4; ++i) {
        r[i]     = (short)__builtin_bit_cast(unsigned short, static_cast<__bf16>(lo[i]));
        r[i + 4] = (short)__builtin_bit_cast(unsigned short, static_cast<__bf16>(hi[i]));
    }
    return r;
}

// ---------------------------------------------------------------------------
// K1 (grid 256): W convert (SWIZZLED layout) + sorted[]=-1 fill + distributed
// partial histogram (blocks 0..63, one 128-elem slice of sel each).
// Swizzle (rule #21, both-sides-or-neither): logical 16B chunk (row, chk) of
// expert tile stored at (row, chk ^ (row&7)). gemm stages LINEARLY via
// global_load_lds and applies the same XOR on ds_read -> 2-way (free) bank
// access instead of 8-way per 16-lane phase.
// ---------------------------------------------------------------------------
__global__ __launch_bounds__(256)
void prep1_kernel(const int* __restrict__ sel, const float* __restrict__ W,
                  short* __restrict__ Wbf, int* __restrict__ sorted,
                  int* __restrict__ gcnt)
{
    const int t   = threadIdx.x;
    const int blk = blockIdx.x;

    // (a) W convert with swizzled chunk placement: 2 iters x 8 floats
    #pragma unroll
    for (int i = 0; i < 2; ++i) {
        const int g8  = blk * 512 + i * 256 + t;   // global 8-elem group id
        const int e   = g8 >> 11;                  // 2048 groups per expert
        const int row = (g8 & 2047) >> 4;          // 16 chunks per 128-row
        const int chk = g8 & 15;
        const float* ws = W + (size_t)g8 * 8;
        f32x4 lo = *reinterpret_cast<const f32x4*>(ws);
        f32x4 hi = *reinterpret_cast<const f32x4*>(ws + 4);
        short* wd = Wbf + ((size_t)e << 14) + row * CH + ((chk ^ (row & 7)) << 3);
        *reinterpret_cast<bf16x8*>(wd) = cvt8(lo, hi);
    }

    // (b) -1 fill of the whole sorted list (pads + tail keep -1 after scatter)
    {
        const int si = blk * 256 + t;
        if (si < MAXP) sorted[si] = -1;
    }

    // (c) partial histogram for slice blk
    if (blk < NSORT) {
        __shared__ int hist[NEXP];
        if (t < NEXP) hist[t] = 0;
        __syncthreads();
        if (t < SLICE) atomicAdd(&hist[sel[blk * SLICE + t]], 1);
        __syncthreads();
        if (t < NEXP) gcnt[blk * NEXP + t] = hist[t];
    }
}

// ---------------------------------------------------------------------------
// K2 (grid 64): padded segment starts from the 64x64 partial-count matrix
// (shfl_up scan) + own cross-block prefix; scatter the 128-node slice.
// ---------------------------------------------------------------------------
__global__ __launch_bounds__(256)
void prep2_kernel(const int* __restrict__ sel, const int* __restrict__ gcnt,
                  int* __restrict__ sorted)
{
    const int t   = threadIdx.x;
    const int blk = blockIdx.x;

    __shared__ int cursor[NEXP];

    if (t < NEXP) {                 // wave 0: one expert per lane
        int cnt = 0, own = 0;
        for (int s = 0; s < NSORT; ++s) {
            int g = gcnt[s * NEXP + t];
            own += (s < blk) ? g : 0;
            cnt += g;
        }
        int p = (cnt + TN - 1) & ~(TN - 1);
        int scan = p;               // inclusive padded scan over 64 experts
        #pragma unroll
        for (int d = 1; d < NEXP; d <<= 1) {
            int v = __shfl_up(scan, d);
            if (t >= d) scan += v;
        }
        cursor[t] = (scan - p) + own;   // segment start + cross-block prefix
    }
    __syncthreads();

    if (t < SLICE) {
        int n = blk * SLICE + t;
        int e = sel[n];
        int pos = atomicAdd(&cursor[e], 1);
        sorted[pos] = n;
    }
}

// ---------------------------------------------------------------------------
// K3: grouped GEMM, D = W . x^T. Block = 16 nodes, 256 threads = 4 waves.
// New in round 5:
//  - W tile (32 KB, pre-swizzled bf16) async-staged to LDS via
//    global_load_lds width=16, one quarter per wave. Kills the 4x-duplicated
//    direct-L2 wfrag gathers (72 MB -> 18 MB L2 traffic).
//  - All 16 x dwordx4 loads issued BEFORE the staging barrier (T14): HBM
//    latency hides under the DMA + barrier drain. Compute phase then runs
//    entirely from regs + LDS.
//  - B-frag ds_read applies chunk XOR (row&7): 2-way banks = free.
// ---------------------------------------------------------------------------
__global__ __launch_bounds__(256)
void gemm_kernel(const float* __restrict__ x, const int* __restrict__ sel,
                 const short* __restrict__ Wbf, float* __restrict__ out,
                 const int* __restrict__ sorted)
{
    __shared__ short s_w[CH * CH];           // 32 KB swizzled W tile
    __shared__ int s_nodes[TN];
    __shared__ int s_expert;

    const int tid  = threadIdx.x;
    const int tile = blockIdx.x;

    if (tid < TN) s_nodes[tid] = sorted[tile * TN + tid];
    if (tid == 0) {
        int n0 = sorted[tile * TN];
        s_expert = (n0 >= 0) ? sel[n0] : -1;
    }
    __syncthreads();

    const int e = s_expert;
    if (e < 0) return;                       // unused tile (uniform per block)

    const int wave = tid >> 6;               // 0..3
    const int lane = tid & 63;
    const int m16  = lane & 15;              // A row (out-ch) / B col (node-row)
    const int quad = lane >> 4;              // k-subblock / D out-ch group

    // x row addresses for this lane's B-operand rows
    int          nodej[2];
    const float* xrow[2];
    #pragma unroll
    for (int jt = 0; jt < 2; ++jt) {
        int j    = wave * 32 + jt * 16 + m16;       // block-local output row
        int node = s_nodes[j >> 3];
        int b    = j & 7;
        nodej[jt] = node;
        int nd   = (node >= 0) ? node : 0;          // safe address for pads
        xrow[jt] = x + ((size_t)(b * NODES + nd)) * CH;
    }

    // (1) issue ALL x loads first — latency hides under W staging
    f32x4 xl[2][4][2];
    #pragma unroll
    for (int jt = 0; jt < 2; ++jt)
        #pragma unroll
        for (int kk = 0; kk < 4; ++kk) {
            const float* p = xrow[jt] + kk * 32 + quad * 8;
            xl[jt][kk][0] = *reinterpret_cast<const f32x4*>(p);
            xl[jt][kk][1] = *reinterpret_cast<const f32x4*>(p + 4);
        }

    // (2) async-stage this expert's swizzled 32 KB W tile; wave w copies 8 KB
    {
        const char* gsrc = (const char*)(Wbf + ((size_t)e << 14))
                         + wave * 8192 + lane * 16;
        char* ldst = (char*)s_w + wave * 8192;
        #pragma unroll
        for (int i = 0; i < 8; ++i) {
            __builtin_amdgcn_global_load_lds(
                (gu32*)(gsrc + i * 1024),
                (lu32*)(ldst + i * 1024),
                16, 0, 0);
        }
    }
    __syncthreads();   // drains vmcnt(0) (x loads + LDS-DMA) + barrier

    // (3) convert x to bf16 fragments (v_cvt_pk)
    bf16x8 xfrag[2][4];
    #pragma unroll
    for (int jt = 0; jt < 2; ++jt)
        #pragma unroll
        for (int kk = 0; kk < 4; ++kk)
            xfrag[jt][kk] = cvt8(xl[jt][kk][0], xl[jt][kk][1]);

    f32x4 acc[2][8];
    #pragma unroll
    for (int jt = 0; jt < 2; ++jt)
        #pragma unroll
        for (int ct = 0; ct < 8; ++ct)
            acc[jt][ct] = (f32x4){0.f, 0.f, 0.f, 0.f};

    // (4) MFMA loop: B-frags from LDS with matching XOR de-swizzle
    #pragma unroll
    for (int kk = 0; kk < 4; ++kk) {
        #pragma unroll
        for (int ct = 0; ct < 8; ++ct) {
            const int row = ct * 16 + m16;
            const bf16x8 wfrag = *reinterpret_cast<const bf16x8*>(
                s_w + row * CH + (((kk * 4 + quad) ^ (row & 7)) << 3));
            acc[0][ct] = __builtin_amdgcn_mfma_f32_16x16x32_bf16(
                             wfrag, xfrag[0][kk], acc[0][ct], 0, 0, 0);
            acc[1][ct] = __builtin_amdgcn_mfma_f32_16x16x32_bf16(
                             wfrag, xfrag[1][kk], acc[1][ct], 0, 0, 0);
        }
    }

    // D layout: col(lane&15) = node-row j, row(quad*4+reg) = out-ch within ct
    // -> lane's f32x4 = out[j][ct*16 + quad*4 .. +3]: one dwordx4 store.
    #pragma unroll
    for (int jt = 0; jt < 2; ++jt) {
        int node = nodej[jt];
        if (node < 0) continue;                     // padded row: drop
        int j = wave * 32 + jt * 16 + m16;
        int b = j & 7;
        float* orow = out + ((size_t)(b * NODES + node)) * CH;
        #pragma unroll
        for (int ct = 0; ct < 8; ++ct)
            *reinterpret_cast<f32x4*>(orow + ct * 16 + quad * 4) = acc[jt][ct];
    }
}

extern "C" void kernel_launch(void* const* d_in, const int* in_sizes, int n_in,
                              void* d_out, int out_size, void* d_ws, size_t ws_size,
                              hipStream_t stream)
{
    const float* x   = (const float*)d_in[0];
    const int*   sel = (const int*)  d_in[1];
    const float* W   = (const float*)d_in[2];
    float*       out = (float*)d_out;

    short* Wbf    = (short*)d_ws;                             // 2 MiB
    int*   sorted = (int*)((char*)d_ws + (size_t)NEXP * CH * CH * sizeof(short));
    int*   gcnt   = sorted + MAXP;                            // 64x64 partials

    prep1_kernel<<<256, 256, 0, stream>>>(sel, W, Wbf, sorted, gcnt);
    prep2_kernel<<<NSORT, 256, 0, stream>>>(sel, gcnt, sorted);
    gemm_kernel<<<NTILES, 256, 0, stream>>>(x, sel, Wbf, out, sorted);
}